// Round 1
// baseline (81.369 us; speedup 1.0000x reference)
//
#include <hip/hip_runtime.h>
#include <math.h>

// ParabolicPool1DFast: B=32, C=64, L=4096, KS=7, STRIDE=2, HALF=3.
//
// Reference semantics (verified absmax 0.0 in prior rounds):
//   dil[b,c,l] = max_{z=-3..3} f[b,c,l+z] - z^2*(0.25/t[c])   (-inf outside [0,L))
//   out[b,c,i] = dil_flat[(b + c) + 2*i]    (faithful as_strided gather)
// Max flat index = 31+63+2*2047 = 4188 -> only f rows (0,0) and (0,1) are
// consumed, 16.8 KB total, fully L1/L2 resident for every block.
//
// Round-4 restructure: the previous kernel rebuilt a 4189-entry dilation
// table in LDS per block (2048x redundant) + __syncthreads + LDS round trip.
// That whole apparatus is removed: each thread now computes its 8 output
// values (2 x float4) directly in registers from the cached f rows.
//   fast path (all but ~2-5 threads/block): all 13 taps inside f row 0,
//     no bounds checks, no -inf handling — 13 cached dword loads + fmax tree.
//   slow path: left border (base<3) and the row-0/row-1 seam near q=4096 —
//     full per-tap bounds/row check, few threads, divergence confined.
// Arithmetic is bit-identical to the verified kernel: c_z = z^2 * (0.25f/t),
// fmax-tree order only permutes exact max operations.
//
// Purpose of this round: disambiguate the 79.5 us floor. The rocprof top-5
// are harness 256 MiB poison fills (~43 us each @ 78% HBM peak); the kernel's
// own roofline is ~5 us (16.78 MB write @ 6.3 TB/s + ~2 us VALU). If dur_us
// does not move, the floor is the harness's, not the kernel's.

#define THREADS 256
#define NBLOCKS 2048            // == number of output rows (32*64)

__global__ __launch_bounds__(THREADS) void ParabolicPool1DFast_kernel(
    const float* __restrict__ f,   // [32,64,4096]; only rows (0,0),(0,1) used
    const float* __restrict__ t,   // [64]; only t[0], t[1] used
    float* __restrict__ out)       // [32,64,2048] flat
{
    const int tid  = threadIdx.x;
    const int r    = (int)blockIdx.x;          // row = bi*64 + ci
    const int base = (r >> 6) + (r & 63);      // bi + ci, in [0,94]
    const float a0 = 0.25f / t[0];
    const float a1 = 0.25f / t[1];
    const float c1 = a0, c2 = 4.0f * a0, c3 = 9.0f * a0;
    float* orow = out + (r << 11);

#pragma unroll
    for (int k = 0; k < 2; ++k) {
        const int i0 = (k * THREADS + tid) * 4;  // 4 consecutive outputs
        const int q0 = base + 2 * i0;            // dil-flat index of output 0
        const int p0 = q0 - 3;                   // first tap flat position
        float v0, v1, v2, v3;

        if (p0 >= 0 && q0 + 9 <= 4095) {
            // ---- fast path: taps p0..p0+12 all inside f row 0, all valid ----
            float w[13];
            const float* fp = f + p0;
#pragma unroll
            for (int v = 0; v < 13; ++v) w[v] = fp[v];
            float r4[4];
#pragma unroll
            for (int j = 0; j < 4; ++j) {
                // output q = q0+2j: window w[2j .. 2j+6], center w[2j+3]
                const float m1 = fmaxf(w[2*j + 2], w[2*j + 4]);
                const float m2 = fmaxf(w[2*j + 1], w[2*j + 5]);
                const float m3 = fmaxf(w[2*j + 0], w[2*j + 6]);
                r4[j] = fmaxf(fmaxf(w[2*j + 3], m1 - c1),
                              fmaxf(m2 - c2, m3 - c3));
            }
            v0 = r4[0]; v1 = r4[1]; v2 = r4[2]; v3 = r4[3];
        } else {
            // ---- slow path: borders + row seam (handful of threads/block) ----
            float r4[4];
#pragma unroll
            for (int j = 0; j < 4; ++j) {
                const int q   = q0 + 2 * j;
                const int row = q >> 12;           // 0 or 1
                const int l   = q & 4095;
                const float aq = row ? a1 : a0;
                const float* frow = f + (row << 12);
                float best = -INFINITY;
#pragma unroll
                for (int zj = 0; zj < 7; ++zj) {
                    const int z  = zj - 3;
                    const int li = l + z;
                    if (li >= 0 && li < 4096)
                        best = fmaxf(best, frow[li] - (float)(z * z) * aq);
                }
                r4[j] = best;
            }
            v0 = r4[0]; v1 = r4[1]; v2 = r4[2]; v3 = r4[3];
        }

        *(float4*)(orow + i0) = make_float4(v0, v1, v2, v3);
    }
}

extern "C" void kernel_launch(void* const* d_in, const int* in_sizes, int n_in,
                              void* d_out, int out_size, void* d_ws, size_t ws_size,
                              hipStream_t stream) {
    const float* f = (const float*)d_in[0];   // [32,64,4096] fp32
    const float* t = (const float*)d_in[1];   // [64] fp32
    float* out = (float*)d_out;               // 4194304 fp32
    ParabolicPool1DFast_kernel<<<NBLOCKS, THREADS, 0, stream>>>(f, t, out);
}